// Round 1
// baseline (810.332 us; speedup 1.0000x reference)
//
#include <hip/hip_runtime.h>
#include <hip/hip_bf16.h>

// ---------------------------------------------------------------------------
// GraphSAGE 3-layer + global mean pool, fp32.
//   layer: agg = mean_{e:dst=n} relu(h[src_e]);  h' = agg@Wl^T + bl + h@Wr^T
//   relu after layers 0,1. Output: h3 [N,40] then g [128,40].
// Plan: CSR-by-dst built once per call; gather-aggregate (no fp32 atomics);
// dual-phase tiled fp32 GEMM with fused bias/relu.
// ---------------------------------------------------------------------------

#define NODES 50000
#define K_DIM 128

__global__ void deg_kernel(const int* __restrict__ dst, int* __restrict__ deg, int E) {
    int e = blockIdx.x * blockDim.x + threadIdx.x;
    if (e < E) atomicAdd(&deg[dst[e]], 1);
}

// single-block scan: 1024 threads, each owns a contiguous chunk
__global__ void scan_kernel(const int* __restrict__ deg, int* __restrict__ rowptr, int N) {
    const int tid = threadIdx.x;
    const int CH = (N + 1023) / 1024;
    int s0 = tid * CH;
    int s1 = s0 + CH; if (s1 > N) s1 = N;
    int sum = 0;
    for (int i = s0; i < s1 && i < N; ++i) sum += deg[i];
    // wave-64 inclusive scan
    int lane = tid & 63, wv = tid >> 6;
    int incl = sum;
    #pragma unroll
    for (int off = 1; off < 64; off <<= 1) {
        int t = __shfl_up(incl, off, 64);
        if (lane >= off) incl += t;
    }
    __shared__ int wsum[16];
    __shared__ int woff[16];
    if (lane == 63) wsum[wv] = incl;
    __syncthreads();
    if (tid == 0) {
        int acc = 0;
        for (int i = 0; i < 16; ++i) { woff[i] = acc; acc += wsum[i]; }
    }
    __syncthreads();
    int run = woff[wv] + incl - sum;   // exclusive prefix at s0
    for (int i = s0; i < s1 && i < N; ++i) { rowptr[i] = run; run += deg[i]; }
    if (tid == 1023) rowptr[N] = run;  // last thread's chunk is empty/clamped -> run == total
}

__global__ void copy_kernel(const int* __restrict__ a, int* __restrict__ b, int N) {
    int i = blockIdx.x * blockDim.x + threadIdx.x;
    if (i < N) b[i] = a[i];
}

__global__ void fill_kernel(const int* __restrict__ src, const int* __restrict__ dst,
                            int* __restrict__ fillpos, int* __restrict__ csr_src, int E) {
    int e = blockIdx.x * blockDim.x + threadIdx.x;
    if (e < E) {
        int p = atomicAdd(&fillpos[dst[e]], 1);
        csr_src[p] = src[e];
    }
}

// one 32-thread group per node; lane handles 4 consecutive feats (float4)
__global__ void agg_kernel(const float* __restrict__ h, const int* __restrict__ rowptr,
                           const int* __restrict__ csr_src, float* __restrict__ agg, int N) {
    int gt = blockIdx.x * blockDim.x + threadIdx.x;
    int group = gt >> 5;
    int lane = threadIdx.x & 31;
    if (group >= N) return;
    int start = rowptr[group], end = rowptr[group + 1];
    float4 acc = make_float4(0.f, 0.f, 0.f, 0.f);
    for (int e = start; e < end; ++e) {
        int s = csr_src[e];
        float4 v = reinterpret_cast<const float4*>(h + (size_t)s * K_DIM)[lane];
        acc.x += fmaxf(v.x, 0.f);
        acc.y += fmaxf(v.y, 0.f);
        acc.z += fmaxf(v.z, 0.f);
        acc.w += fmaxf(v.w, 0.f);
    }
    float inv = 1.0f / fmaxf((float)(end - start), 1.0f);
    acc.x *= inv; acc.y *= inv; acc.z *= inv; acc.w *= inv;
    reinterpret_cast<float4*>(agg + (size_t)group * K_DIM)[lane] = acc;
}

// out[m,n] = sum_k A[m,k]*Wl[n,k] + bl[n] + sum_k H[m,k]*Wr[n,k]  (opt relu)
template <int BM, int BN, int BK, int TM, int TN, int DOUT, bool RELU>
__global__ __launch_bounds__(256) void sage_gemm(
        const float* __restrict__ A, const float* __restrict__ H,
        const float* __restrict__ Wl, const float* __restrict__ Wr,
        const float* __restrict__ bl, float* __restrict__ out, int N) {
    constexpr int K = K_DIM;
    const int tid = threadIdx.x;
    const int tx = tid % (BN / TN);
    const int ty = tid / (BN / TN);
    const int m0 = blockIdx.x * BM;

    __shared__ __align__(16) float As[BK][BM + 4];
    __shared__ __align__(16) float Ws[BK][BN + 4];

    float acc[TM][TN];
    #pragma unroll
    for (int i = 0; i < TM; ++i)
        #pragma unroll
        for (int j = 0; j < TN; ++j) acc[i][j] = 0.f;

    #pragma unroll
    for (int phase = 0; phase < 2; ++phase) {
        const float* __restrict__ X = phase ? H : A;
        const float* __restrict__ W = phase ? Wr : Wl;
        for (int k0 = 0; k0 < K; k0 += BK) {
            // stage X tile (BM x BK) transposed into As[k][m]
            #pragma unroll
            for (int q = tid; q < BM * BK / 4; q += 256) {
                int row = q / (BK / 4);
                int c4  = q % (BK / 4);
                int m = m0 + row;
                float4 v = make_float4(0.f, 0.f, 0.f, 0.f);
                if (m < N) v = *reinterpret_cast<const float4*>(X + (size_t)m * K + k0 + c4 * 4);
                As[c4 * 4 + 0][row] = v.x;
                As[c4 * 4 + 1][row] = v.y;
                As[c4 * 4 + 2][row] = v.z;
                As[c4 * 4 + 3][row] = v.w;
            }
            // stage W tile (BN x BK) transposed into Ws[k][n]
            #pragma unroll
            for (int q = tid; q < BN * BK / 4; q += 256) {
                int row = q / (BK / 4);
                int c4  = q % (BK / 4);
                float4 v = make_float4(0.f, 0.f, 0.f, 0.f);
                if (row < DOUT) v = *reinterpret_cast<const float4*>(W + (size_t)row * K + k0 + c4 * 4);
                Ws[c4 * 4 + 0][row] = v.x;
                Ws[c4 * 4 + 1][row] = v.y;
                Ws[c4 * 4 + 2][row] = v.z;
                Ws[c4 * 4 + 3][row] = v.w;
            }
            __syncthreads();
            #pragma unroll
            for (int kk = 0; kk < BK; ++kk) {
                float a[TM], w[TN];
                #pragma unroll
                for (int i = 0; i < TM; i += 4) {
                    float4 t = *reinterpret_cast<const float4*>(&As[kk][ty * TM + i]);
                    a[i] = t.x; a[i + 1] = t.y; a[i + 2] = t.z; a[i + 3] = t.w;
                }
                #pragma unroll
                for (int j = 0; j < TN; j += 4) {
                    float4 t = *reinterpret_cast<const float4*>(&Ws[kk][tx * TN + j]);
                    w[j] = t.x; w[j + 1] = t.y; w[j + 2] = t.z; w[j + 3] = t.w;
                }
                #pragma unroll
                for (int i = 0; i < TM; ++i)
                    #pragma unroll
                    for (int j = 0; j < TN; ++j) acc[i][j] = fmaf(a[i], w[j], acc[i][j]);
            }
            __syncthreads();
        }
    }

    float bias[TN];
    #pragma unroll
    for (int j = 0; j < TN; ++j) {
        int n = tx * TN + j;
        bias[j] = (n < DOUT) ? bl[n] : 0.f;
    }
    #pragma unroll
    for (int i = 0; i < TM; ++i) {
        int m = m0 + ty * TM + i;
        if (m >= N) continue;
        #pragma unroll
        for (int j = 0; j < TN; j += 4) {
            int n = tx * TN + j;
            if (n < DOUT) {  // DOUT % 4 == 0, so whole float4 is in or out
                float4 v;
                v.x = acc[i][j + 0] + bias[j + 0];
                v.y = acc[i][j + 1] + bias[j + 1];
                v.z = acc[i][j + 2] + bias[j + 2];
                v.w = acc[i][j + 3] + bias[j + 3];
                if (RELU) {
                    v.x = fmaxf(v.x, 0.f); v.y = fmaxf(v.y, 0.f);
                    v.z = fmaxf(v.z, 0.f); v.w = fmaxf(v.w, 0.f);
                }
                *reinterpret_cast<float4*>(out + (size_t)m * DOUT + n) = v;
            }
        }
    }
}

__global__ void pool_scatter(const float* __restrict__ h, const int* __restrict__ batch,
                             float* __restrict__ gsum, float* __restrict__ gcnt, int N) {
    int n = blockIdx.x;
    int c = threadIdx.x;
    if (n >= N) return;
    int b = batch[n];
    if (c < 40) atomicAdd(&gsum[b * 40 + c], h[(size_t)n * 40 + c]);
    if (c == 0) atomicAdd(&gcnt[b], 1.0f);
}

__global__ void pool_div(float* __restrict__ gsum, const float* __restrict__ gcnt) {
    int i = blockIdx.x * blockDim.x + threadIdx.x;
    if (i < 128 * 40) {
        int b = i / 40;
        gsum[i] /= fmaxf(gcnt[b], 1.0f);
    }
}

extern "C" void kernel_launch(void* const* d_in, const int* in_sizes, int n_in,
                              void* d_out, int out_size, void* d_ws, size_t ws_size,
                              hipStream_t stream) {
    const float* x    = (const float*)d_in[0];
    const int*   ei   = (const int*)d_in[1];
    const int*   batch= (const int*)d_in[2];
    const float* Wl0  = (const float*)d_in[3];
    const float* bl0  = (const float*)d_in[4];
    const float* Wr0  = (const float*)d_in[5];
    const float* Wl1  = (const float*)d_in[6];
    const float* bl1  = (const float*)d_in[7];
    const float* Wr1  = (const float*)d_in[8];
    const float* Wl2  = (const float*)d_in[9];
    const float* bl2  = (const float*)d_in[10];
    const float* Wr2  = (const float*)d_in[11];

    const int N = in_sizes[0] / K_DIM;       // 50000
    const int E = in_sizes[1] / 2;           // 600000
    const int* src = ei;
    const int* dst = ei + E;

    float* out = (float*)d_out;              // h3 [N,40] then g [128,40]
    float* gsum = out + (size_t)N * 40;

    // carve workspace (256B aligned regions)
    char* w = (char*)d_ws;
    auto alloc = [&](size_t bytes) {
        char* p = w;
        w += (bytes + 255) & ~(size_t)255;
        return p;
    };
    float* bufA  = (float*)alloc((size_t)N * K_DIM * 4);  // agg (all layers)
    float* bufB  = (float*)alloc((size_t)N * K_DIM * 4);  // h1
    float* bufC  = (float*)alloc((size_t)N * K_DIM * 4);  // h2
    int*   rowptr= (int*)alloc((size_t)(N + 1) * 4);
    int*   deg   = (int*)alloc((size_t)N * 4);            // reused as fillpos
    int*   csr   = (int*)alloc((size_t)E * 4);
    float* gcnt  = (float*)alloc(128 * 4);

    hipMemsetAsync(deg, 0, (size_t)N * 4, stream);
    hipMemsetAsync(gcnt, 0, 128 * 4, stream);
    hipMemsetAsync(gsum, 0, 128 * 40 * 4, stream);

    // build CSR by dst
    deg_kernel<<<(E + 255) / 256, 256, 0, stream>>>(dst, deg, E);
    scan_kernel<<<1, 1024, 0, stream>>>(deg, rowptr, N);
    copy_kernel<<<(N + 255) / 256, 256, 0, stream>>>(rowptr, deg, N);
    fill_kernel<<<(E + 255) / 256, 256, 0, stream>>>(src, dst, deg, csr, E);

    const int aggGrid  = (N * 32 + 255) / 256;
    const int gemmGrid = (N + 63) / 64;

    // layer 0
    agg_kernel<<<aggGrid, 256, 0, stream>>>(x, rowptr, csr, bufA, N);
    sage_gemm<64, 128, 16, 4, 8, 128, true><<<gemmGrid, 256, 0, stream>>>(
        bufA, x, Wl0, Wr0, bl0, bufB, N);
    // layer 1
    agg_kernel<<<aggGrid, 256, 0, stream>>>(bufB, rowptr, csr, bufA, N);
    sage_gemm<64, 128, 16, 4, 8, 128, true><<<gemmGrid, 256, 0, stream>>>(
        bufA, bufB, Wl1, Wr1, bl1, bufC, N);
    // layer 2 (writes node output directly to d_out)
    agg_kernel<<<aggGrid, 256, 0, stream>>>(bufC, rowptr, csr, bufA, N);
    sage_gemm<64, 64, 16, 4, 4, 40, false><<<gemmGrid, 256, 0, stream>>>(
        bufA, bufC, Wl2, Wr2, bl2, out, N);

    // global mean pool
    pool_scatter<<<N, 64, 0, stream>>>(out, batch, gsum, gcnt, N);
    pool_div<<<(128 * 40 + 255) / 256, 256, 0, stream>>>(gsum, gcnt);
}

// Round 2
// 536.953 us; speedup vs baseline: 1.5091x; 1.5091x over previous
//
#include <hip/hip_runtime.h>
#include <hip/hip_bf16.h>

// ---------------------------------------------------------------------------
// GraphSAGE 3-layer + global mean pool, fp32.
//   layer: agg = mean_{e:dst=n} relu(h[src_e]);  h' = agg@Wl^T + bl + h@Wr^T
//   relu after layers 0,1. Output: h3 [N,40] then g [128,40].
// R1: batch is SORTED -> replace atomic pool_scatter (287us of contention;
// VALUBusy 0.3%) with segment-boundary binary search + per-graph block
// reduction (no atomics).
// ---------------------------------------------------------------------------

#define NODES 50000
#define K_DIM 128
#define N_GRAPHS 128

__global__ void deg_kernel(const int* __restrict__ dst, int* __restrict__ deg, int E) {
    int e = blockIdx.x * blockDim.x + threadIdx.x;
    if (e < E) atomicAdd(&deg[dst[e]], 1);
}

// single-block scan: 1024 threads, each owns a contiguous chunk
__global__ void scan_kernel(const int* __restrict__ deg, int* __restrict__ rowptr, int N) {
    const int tid = threadIdx.x;
    const int CH = (N + 1023) / 1024;
    int s0 = tid * CH;
    int s1 = s0 + CH; if (s1 > N) s1 = N;
    int sum = 0;
    for (int i = s0; i < s1 && i < N; ++i) sum += deg[i];
    // wave-64 inclusive scan
    int lane = tid & 63, wv = tid >> 6;
    int incl = sum;
    #pragma unroll
    for (int off = 1; off < 64; off <<= 1) {
        int t = __shfl_up(incl, off, 64);
        if (lane >= off) incl += t;
    }
    __shared__ int wsum[16];
    __shared__ int woff[16];
    if (lane == 63) wsum[wv] = incl;
    __syncthreads();
    if (tid == 0) {
        int acc = 0;
        for (int i = 0; i < 16; ++i) { woff[i] = acc; acc += wsum[i]; }
    }
    __syncthreads();
    int run = woff[wv] + incl - sum;   // exclusive prefix at s0
    for (int i = s0; i < s1 && i < N; ++i) { rowptr[i] = run; run += deg[i]; }
    if (tid == 1023) rowptr[N] = run;
}

__global__ void copy_kernel(const int* __restrict__ a, int* __restrict__ b, int N) {
    int i = blockIdx.x * blockDim.x + threadIdx.x;
    if (i < N) b[i] = a[i];
}

__global__ void fill_kernel(const int* __restrict__ src, const int* __restrict__ dst,
                            int* __restrict__ fillpos, int* __restrict__ csr_src, int E) {
    int e = blockIdx.x * blockDim.x + threadIdx.x;
    if (e < E) {
        int p = atomicAdd(&fillpos[dst[e]], 1);
        csr_src[p] = src[e];
    }
}

// one 32-thread group per node; lane handles 4 consecutive feats (float4)
__global__ void agg_kernel(const float* __restrict__ h, const int* __restrict__ rowptr,
                           const int* __restrict__ csr_src, float* __restrict__ agg, int N) {
    int gt = blockIdx.x * blockDim.x + threadIdx.x;
    int group = gt >> 5;
    int lane = threadIdx.x & 31;
    if (group >= N) return;
    int start = rowptr[group], end = rowptr[group + 1];
    float4 acc = make_float4(0.f, 0.f, 0.f, 0.f);
    for (int e = start; e < end; ++e) {
        int s = csr_src[e];
        float4 v = reinterpret_cast<const float4*>(h + (size_t)s * K_DIM)[lane];
        acc.x += fmaxf(v.x, 0.f);
        acc.y += fmaxf(v.y, 0.f);
        acc.z += fmaxf(v.z, 0.f);
        acc.w += fmaxf(v.w, 0.f);
    }
    float inv = 1.0f / fmaxf((float)(end - start), 1.0f);
    acc.x *= inv; acc.y *= inv; acc.z *= inv; acc.w *= inv;
    reinterpret_cast<float4*>(agg + (size_t)group * K_DIM)[lane] = acc;
}

// out[m,n] = sum_k A[m,k]*Wl[n,k] + bl[n] + sum_k H[m,k]*Wr[n,k]  (opt relu)
template <int BM, int BN, int BK, int TM, int TN, int DOUT, bool RELU>
__global__ __launch_bounds__(256) void sage_gemm(
        const float* __restrict__ A, const float* __restrict__ H,
        const float* __restrict__ Wl, const float* __restrict__ Wr,
        const float* __restrict__ bl, float* __restrict__ out, int N) {
    constexpr int K = K_DIM;
    const int tid = threadIdx.x;
    const int tx = tid % (BN / TN);
    const int ty = tid / (BN / TN);
    const int m0 = blockIdx.x * BM;

    __shared__ __align__(16) float As[BK][BM + 4];
    __shared__ __align__(16) float Ws[BK][BN + 4];

    float acc[TM][TN];
    #pragma unroll
    for (int i = 0; i < TM; ++i)
        #pragma unroll
        for (int j = 0; j < TN; ++j) acc[i][j] = 0.f;

    #pragma unroll
    for (int phase = 0; phase < 2; ++phase) {
        const float* __restrict__ X = phase ? H : A;
        const float* __restrict__ W = phase ? Wr : Wl;
        for (int k0 = 0; k0 < K; k0 += BK) {
            #pragma unroll
            for (int q = tid; q < BM * BK / 4; q += 256) {
                int row = q / (BK / 4);
                int c4  = q % (BK / 4);
                int m = m0 + row;
                float4 v = make_float4(0.f, 0.f, 0.f, 0.f);
                if (m < N) v = *reinterpret_cast<const float4*>(X + (size_t)m * K + k0 + c4 * 4);
                As[c4 * 4 + 0][row] = v.x;
                As[c4 * 4 + 1][row] = v.y;
                As[c4 * 4 + 2][row] = v.z;
                As[c4 * 4 + 3][row] = v.w;
            }
            #pragma unroll
            for (int q = tid; q < BN * BK / 4; q += 256) {
                int row = q / (BK / 4);
                int c4  = q % (BK / 4);
                float4 v = make_float4(0.f, 0.f, 0.f, 0.f);
                if (row < DOUT) v = *reinterpret_cast<const float4*>(W + (size_t)row * K + k0 + c4 * 4);
                Ws[c4 * 4 + 0][row] = v.x;
                Ws[c4 * 4 + 1][row] = v.y;
                Ws[c4 * 4 + 2][row] = v.z;
                Ws[c4 * 4 + 3][row] = v.w;
            }
            __syncthreads();
            #pragma unroll
            for (int kk = 0; kk < BK; ++kk) {
                float a[TM], w[TN];
                #pragma unroll
                for (int i = 0; i < TM; i += 4) {
                    float4 t = *reinterpret_cast<const float4*>(&As[kk][ty * TM + i]);
                    a[i] = t.x; a[i + 1] = t.y; a[i + 2] = t.z; a[i + 3] = t.w;
                }
                #pragma unroll
                for (int j = 0; j < TN; j += 4) {
                    float4 t = *reinterpret_cast<const float4*>(&Ws[kk][tx * TN + j]);
                    w[j] = t.x; w[j + 1] = t.y; w[j + 2] = t.z; w[j + 3] = t.w;
                }
                #pragma unroll
                for (int i = 0; i < TM; ++i)
                    #pragma unroll
                    for (int j = 0; j < TN; ++j) acc[i][j] = fmaf(a[i], w[j], acc[i][j]);
            }
            __syncthreads();
        }
    }

    float bias[TN];
    #pragma unroll
    for (int j = 0; j < TN; ++j) {
        int n = tx * TN + j;
        bias[j] = (n < DOUT) ? bl[n] : 0.f;
    }
    #pragma unroll
    for (int i = 0; i < TM; ++i) {
        int m = m0 + ty * TM + i;
        if (m >= N) continue;
        #pragma unroll
        for (int j = 0; j < TN; j += 4) {
            int n = tx * TN + j;
            if (n < DOUT) {  // DOUT % 4 == 0, so whole float4 is in or out
                float4 v;
                v.x = acc[i][j + 0] + bias[j + 0];
                v.y = acc[i][j + 1] + bias[j + 1];
                v.z = acc[i][j + 2] + bias[j + 2];
                v.w = acc[i][j + 3] + bias[j + 3];
                if (RELU) {
                    v.x = fmaxf(v.x, 0.f); v.y = fmaxf(v.y, 0.f);
                    v.z = fmaxf(v.z, 0.f); v.w = fmaxf(v.w, 0.f);
                }
                *reinterpret_cast<float4*>(out + (size_t)m * DOUT + n) = v;
            }
        }
    }
}

// batch is sorted -> graph g occupies nodes [gstart[g], gstart[g+1])
__global__ void bounds_kernel(const int* __restrict__ batch, int* __restrict__ gstart, int N) {
    int g = blockIdx.x * blockDim.x + threadIdx.x;
    if (g > N_GRAPHS) return;
    int lo = 0, hi = N;
    while (lo < hi) {
        int mid = (lo + hi) >> 1;
        if (batch[mid] < g) lo = mid + 1; else hi = mid;
    }
    gstart[g] = lo;
}

// one block (8 rows x 40 channels = 320 threads) per graph; coalesced, no atomics
__global__ __launch_bounds__(320) void pool_kernel(const float* __restrict__ h,
                                                   const int* __restrict__ gstart,
                                                   float* __restrict__ g_out) {
    int g = blockIdx.x;
    int tid = threadIdx.x;
    int c = tid % 40, r = tid / 40;
    int s = gstart[g], e = gstart[g + 1];
    float acc = 0.f;
    for (int n = s + r; n < e; n += 8)
        acc += h[(size_t)n * 40 + c];
    __shared__ float sh[8][40];
    sh[r][c] = acc;
    __syncthreads();
    if (r == 0) {
        float sum = 0.f;
        #pragma unroll
        for (int i = 0; i < 8; ++i) sum += sh[i][c];
        g_out[g * 40 + c] = sum / fmaxf((float)(e - s), 1.0f);
    }
}

extern "C" void kernel_launch(void* const* d_in, const int* in_sizes, int n_in,
                              void* d_out, int out_size, void* d_ws, size_t ws_size,
                              hipStream_t stream) {
    const float* x    = (const float*)d_in[0];
    const int*   ei   = (const int*)d_in[1];
    const int*   batch= (const int*)d_in[2];
    const float* Wl0  = (const float*)d_in[3];
    const float* bl0  = (const float*)d_in[4];
    const float* Wr0  = (const float*)d_in[5];
    const float* Wl1  = (const float*)d_in[6];
    const float* bl1  = (const float*)d_in[7];
    const float* Wr1  = (const float*)d_in[8];
    const float* Wl2  = (const float*)d_in[9];
    const float* bl2  = (const float*)d_in[10];
    const float* Wr2  = (const float*)d_in[11];

    const int N = in_sizes[0] / K_DIM;       // 50000
    const int E = in_sizes[1] / 2;           // 600000
    const int* src = ei;
    const int* dst = ei + E;

    float* out = (float*)d_out;              // h3 [N,40] then g [128,40]
    float* gsum = out + (size_t)N * 40;

    // carve workspace (256B aligned regions)
    char* w = (char*)d_ws;
    auto alloc = [&](size_t bytes) {
        char* p = w;
        w += (bytes + 255) & ~(size_t)255;
        return p;
    };
    float* bufA  = (float*)alloc((size_t)N * K_DIM * 4);  // agg (all layers)
    float* bufB  = (float*)alloc((size_t)N * K_DIM * 4);  // h1
    float* bufC  = (float*)alloc((size_t)N * K_DIM * 4);  // h2
    int*   rowptr= (int*)alloc((size_t)(N + 1) * 4);
    int*   deg   = (int*)alloc((size_t)N * 4);            // reused as fillpos
    int*   csr   = (int*)alloc((size_t)E * 4);
    int*   gstart= (int*)alloc((size_t)(N_GRAPHS + 1) * 4);

    hipMemsetAsync(deg, 0, (size_t)N * 4, stream);

    // build CSR by dst
    deg_kernel<<<(E + 255) / 256, 256, 0, stream>>>(dst, deg, E);
    scan_kernel<<<1, 1024, 0, stream>>>(deg, rowptr, N);
    copy_kernel<<<(N + 255) / 256, 256, 0, stream>>>(rowptr, deg, N);
    fill_kernel<<<(E + 255) / 256, 256, 0, stream>>>(src, dst, deg, csr, E);
    bounds_kernel<<<1, 192, 0, stream>>>(batch, gstart, N);

    const int aggGrid  = (N * 32 + 255) / 256;
    const int gemmGrid = (N + 63) / 64;

    // layer 0
    agg_kernel<<<aggGrid, 256, 0, stream>>>(x, rowptr, csr, bufA, N);
    sage_gemm<64, 128, 16, 4, 8, 128, true><<<gemmGrid, 256, 0, stream>>>(
        bufA, x, Wl0, Wr0, bl0, bufB, N);
    // layer 1
    agg_kernel<<<aggGrid, 256, 0, stream>>>(bufB, rowptr, csr, bufA, N);
    sage_gemm<64, 128, 16, 4, 8, 128, true><<<gemmGrid, 256, 0, stream>>>(
        bufA, bufB, Wl1, Wr1, bl1, bufC, N);
    // layer 2 (writes node output directly to d_out)
    agg_kernel<<<aggGrid, 256, 0, stream>>>(bufC, rowptr, csr, bufA, N);
    sage_gemm<64, 64, 16, 4, 4, 40, false><<<gemmGrid, 256, 0, stream>>>(
        bufA, bufC, Wl2, Wr2, bl2, out, N);

    // global mean pool (batch sorted -> contiguous segments)
    pool_kernel<<<N_GRAPHS, 320, 0, stream>>>(out, gstart, gsum);
}

// Round 3
// 448.883 us; speedup vs baseline: 1.8052x; 1.1962x over previous
//
#include <hip/hip_runtime.h>
#include <hip/hip_bf16.h>

// ---------------------------------------------------------------------------
// GraphSAGE 3-layer + global mean pool, fp32.
//   layer: agg = mean_{e:dst=n} relu(h[src_e]);  h' = agg@Wl^T + bl + h@Wr^T
//   relu after layers 0,1. Output: h3 [N,40] then g [128,40].
// R1: sorted-batch pool -> segment reduction (no atomics).  810->537us
// R2: (a) 3-phase parallel scan (old single-block scan was 76us, one CU,
//     latency-bound); (b) agg = one wave64 per node, 2 edges/iter + unroll2
//     (old: 32-lane groups, divergent pairs, serial dependent gathers at
//     4GB/s); (c) ReLU in agg only for layer 0 (h1,h2 already ReLU'd).
// ---------------------------------------------------------------------------

#define NODES 50000
#define K_DIM 128
#define N_GRAPHS 128

__global__ void deg_kernel(const int* __restrict__ dst, int* __restrict__ deg, int E) {
    int e = blockIdx.x * blockDim.x + threadIdx.x;
    if (e < E) atomicAdd(&deg[dst[e]], 1);
}

// --- 3-phase scan: P1 per-block sums, P2 scan block sums, P3 write offsets ---
__global__ void scan_p1(const int* __restrict__ deg, int* __restrict__ bsum, int N) {
    int i = blockIdx.x * 256 + threadIdx.x;
    int v = (i < N) ? deg[i] : 0;
    #pragma unroll
    for (int off = 32; off > 0; off >>= 1) v += __shfl_down(v, off, 64);
    __shared__ int ws[4];
    int lane = threadIdx.x & 63, wv = threadIdx.x >> 6;
    if (lane == 0) ws[wv] = v;
    __syncthreads();
    if (threadIdx.x == 0) bsum[blockIdx.x] = ws[0] + ws[1] + ws[2] + ws[3];
}

// NB <= 256: one block exclusive-scans the block sums in place
__global__ void scan_p2(int* __restrict__ bsum, int NB) {
    int tid = threadIdx.x, lane = tid & 63, wv = tid >> 6;
    int v = (tid < NB) ? bsum[tid] : 0;
    int incl = v;
    #pragma unroll
    for (int off = 1; off < 64; off <<= 1) {
        int t = __shfl_up(incl, off, 64);
        if (lane >= off) incl += t;
    }
    __shared__ int ws[4];
    if (lane == 63) ws[wv] = incl;
    __syncthreads();
    int add = 0;
    for (int i = 0; i < wv; ++i) add += ws[i];
    incl += add;
    if (tid < NB) bsum[tid] = incl - v;   // exclusive
}

// writes rowptr[0..N] and fillpos[0..N-1]
__global__ void scan_p3(const int* __restrict__ deg, const int* __restrict__ boff,
                        int* __restrict__ rowptr, int* __restrict__ fillpos, int N) {
    int i = blockIdx.x * 256 + threadIdx.x;
    int tid = threadIdx.x, lane = tid & 63, wv = tid >> 6;
    int v = (i < N) ? deg[i] : 0;
    int incl = v;
    #pragma unroll
    for (int off = 1; off < 64; off <<= 1) {
        int t = __shfl_up(incl, off, 64);
        if (lane >= off) incl += t;
    }
    __shared__ int ws[4];
    if (lane == 63) ws[wv] = incl;
    __syncthreads();
    int add = 0;
    for (int k = 0; k < wv; ++k) add += ws[k];
    int excl = boff[blockIdx.x] + incl + add - v;
    if (i < N) { rowptr[i] = excl; fillpos[i] = excl; }
    if (i == N) rowptr[N] = excl;
}

__global__ void fill_kernel(const int* __restrict__ src, const int* __restrict__ dst,
                            int* __restrict__ fillpos, int* __restrict__ csr_src, int E) {
    int e = blockIdx.x * blockDim.x + threadIdx.x;
    if (e < E) {
        int p = atomicAdd(&fillpos[dst[e]], 1);
        csr_src[p] = src[e];
    }
}

// one wave64 per node: halves own alternating edges (2/iter), unroll 2.
template <bool RELU>
__global__ void agg_kernel(const float* __restrict__ h, const int* __restrict__ rowptr,
                           const int* __restrict__ csr_src, float* __restrict__ agg, int N) {
    int w = (blockIdx.x * blockDim.x + threadIdx.x) >> 6;
    if (w >= N) return;
    int lane = threadIdx.x & 63;
    int half = lane >> 5, l32 = lane & 31;
    int s = rowptr[w], e = rowptr[w + 1];
    float4 acc = make_float4(0.f, 0.f, 0.f, 0.f);
    int i = s + half;
    for (; i + 2 < e; i += 4) {
        int s0 = csr_src[i], s1 = csr_src[i + 2];
        float4 v0 = reinterpret_cast<const float4*>(h + (size_t)s0 * K_DIM)[l32];
        float4 v1 = reinterpret_cast<const float4*>(h + (size_t)s1 * K_DIM)[l32];
        if (RELU) {
            acc.x += fmaxf(v0.x, 0.f) + fmaxf(v1.x, 0.f);
            acc.y += fmaxf(v0.y, 0.f) + fmaxf(v1.y, 0.f);
            acc.z += fmaxf(v0.z, 0.f) + fmaxf(v1.z, 0.f);
            acc.w += fmaxf(v0.w, 0.f) + fmaxf(v1.w, 0.f);
        } else {
            acc.x += v0.x + v1.x; acc.y += v0.y + v1.y;
            acc.z += v0.z + v1.z; acc.w += v0.w + v1.w;
        }
    }
    for (; i < e; i += 2) {
        int s0 = csr_src[i];
        float4 v0 = reinterpret_cast<const float4*>(h + (size_t)s0 * K_DIM)[l32];
        if (RELU) {
            acc.x += fmaxf(v0.x, 0.f); acc.y += fmaxf(v0.y, 0.f);
            acc.z += fmaxf(v0.z, 0.f); acc.w += fmaxf(v0.w, 0.f);
        } else {
            acc.x += v0.x; acc.y += v0.y; acc.z += v0.z; acc.w += v0.w;
        }
    }
    acc.x += __shfl_xor(acc.x, 32, 64);
    acc.y += __shfl_xor(acc.y, 32, 64);
    acc.z += __shfl_xor(acc.z, 32, 64);
    acc.w += __shfl_xor(acc.w, 32, 64);
    if (half == 0) {
        float inv = 1.0f / fmaxf((float)(e - s), 1.0f);
        acc.x *= inv; acc.y *= inv; acc.z *= inv; acc.w *= inv;
        reinterpret_cast<float4*>(agg + (size_t)w * K_DIM)[l32] = acc;
    }
}

// out[m,n] = sum_k A[m,k]*Wl[n,k] + bl[n] + sum_k H[m,k]*Wr[n,k]  (opt relu)
template <int BM, int BN, int BK, int TM, int TN, int DOUT, bool RELU>
__global__ __launch_bounds__(256) void sage_gemm(
        const float* __restrict__ A, const float* __restrict__ H,
        const float* __restrict__ Wl, const float* __restrict__ Wr,
        const float* __restrict__ bl, float* __restrict__ out, int N) {
    constexpr int K = K_DIM;
    const int tid = threadIdx.x;
    const int tx = tid % (BN / TN);
    const int ty = tid / (BN / TN);
    const int m0 = blockIdx.x * BM;

    __shared__ __align__(16) float As[BK][BM + 4];
    __shared__ __align__(16) float Ws[BK][BN + 4];

    float acc[TM][TN];
    #pragma unroll
    for (int i = 0; i < TM; ++i)
        #pragma unroll
        for (int j = 0; j < TN; ++j) acc[i][j] = 0.f;

    #pragma unroll
    for (int phase = 0; phase < 2; ++phase) {
        const float* __restrict__ X = phase ? H : A;
        const float* __restrict__ W = phase ? Wr : Wl;
        for (int k0 = 0; k0 < K; k0 += BK) {
            #pragma unroll
            for (int q = tid; q < BM * BK / 4; q += 256) {
                int row = q / (BK / 4);
                int c4  = q % (BK / 4);
                int m = m0 + row;
                float4 v = make_float4(0.f, 0.f, 0.f, 0.f);
                if (m < N) v = *reinterpret_cast<const float4*>(X + (size_t)m * K + k0 + c4 * 4);
                As[c4 * 4 + 0][row] = v.x;
                As[c4 * 4 + 1][row] = v.y;
                As[c4 * 4 + 2][row] = v.z;
                As[c4 * 4 + 3][row] = v.w;
            }
            #pragma unroll
            for (int q = tid; q < BN * BK / 4; q += 256) {
                int row = q / (BK / 4);
                int c4  = q % (BK / 4);
                float4 v = make_float4(0.f, 0.f, 0.f, 0.f);
                if (row < DOUT) v = *reinterpret_cast<const float4*>(W + (size_t)row * K + k0 + c4 * 4);
                Ws[c4 * 4 + 0][row] = v.x;
                Ws[c4 * 4 + 1][row] = v.y;
                Ws[c4 * 4 + 2][row] = v.z;
                Ws[c4 * 4 + 3][row] = v.w;
            }
            __syncthreads();
            #pragma unroll
            for (int kk = 0; kk < BK; ++kk) {
                float a[TM], w[TN];
                #pragma unroll
                for (int i = 0; i < TM; i += 4) {
                    float4 t = *reinterpret_cast<const float4*>(&As[kk][ty * TM + i]);
                    a[i] = t.x; a[i + 1] = t.y; a[i + 2] = t.z; a[i + 3] = t.w;
                }
                #pragma unroll
                for (int j = 0; j < TN; j += 4) {
                    float4 t = *reinterpret_cast<const float4*>(&Ws[kk][tx * TN + j]);
                    w[j] = t.x; w[j + 1] = t.y; w[j + 2] = t.z; w[j + 3] = t.w;
                }
                #pragma unroll
                for (int i = 0; i < TM; ++i)
                    #pragma unroll
                    for (int j = 0; j < TN; ++j) acc[i][j] = fmaf(a[i], w[j], acc[i][j]);
            }
            __syncthreads();
        }
    }

    float bias[TN];
    #pragma unroll
    for (int j = 0; j < TN; ++j) {
        int n = tx * TN + j;
        bias[j] = (n < DOUT) ? bl[n] : 0.f;
    }
    #pragma unroll
    for (int i = 0; i < TM; ++i) {
        int m = m0 + ty * TM + i;
        if (m >= N) continue;
        #pragma unroll
        for (int j = 0; j < TN; j += 4) {
            int n = tx * TN + j;
            if (n < DOUT) {  // DOUT % 4 == 0, so whole float4 is in or out
                float4 v;
                v.x = acc[i][j + 0] + bias[j + 0];
                v.y = acc[i][j + 1] + bias[j + 1];
                v.z = acc[i][j + 2] + bias[j + 2];
                v.w = acc[i][j + 3] + bias[j + 3];
                if (RELU) {
                    v.x = fmaxf(v.x, 0.f); v.y = fmaxf(v.y, 0.f);
                    v.z = fmaxf(v.z, 0.f); v.w = fmaxf(v.w, 0.f);
                }
                *reinterpret_cast<float4*>(out + (size_t)m * DOUT + n) = v;
            }
        }
    }
}

// batch is sorted -> graph g occupies nodes [gstart[g], gstart[g+1])
__global__ void bounds_kernel(const int* __restrict__ batch, int* __restrict__ gstart, int N) {
    int g = blockIdx.x * blockDim.x + threadIdx.x;
    if (g > N_GRAPHS) return;
    int lo = 0, hi = N;
    while (lo < hi) {
        int mid = (lo + hi) >> 1;
        if (batch[mid] < g) lo = mid + 1; else hi = mid;
    }
    gstart[g] = lo;
}

// one block (8 rows x 40 channels = 320 threads) per graph; coalesced, no atomics
__global__ __launch_bounds__(320) void pool_kernel(const float* __restrict__ h,
                                                   const int* __restrict__ gstart,
                                                   float* __restrict__ g_out) {
    int g = blockIdx.x;
    int tid = threadIdx.x;
    int c = tid % 40, r = tid / 40;
    int s = gstart[g], e = gstart[g + 1];
    float acc = 0.f;
    for (int n = s + r; n < e; n += 8)
        acc += h[(size_t)n * 40 + c];
    __shared__ float sh[8][40];
    sh[r][c] = acc;
    __syncthreads();
    if (r == 0) {
        float sum = 0.f;
        #pragma unroll
        for (int i = 0; i < 8; ++i) sum += sh[i][c];
        g_out[g * 40 + c] = sum / fmaxf((float)(e - s), 1.0f);
    }
}

extern "C" void kernel_launch(void* const* d_in, const int* in_sizes, int n_in,
                              void* d_out, int out_size, void* d_ws, size_t ws_size,
                              hipStream_t stream) {
    const float* x    = (const float*)d_in[0];
    const int*   ei   = (const int*)d_in[1];
    const int*   batch= (const int*)d_in[2];
    const float* Wl0  = (const float*)d_in[3];
    const float* bl0  = (const float*)d_in[4];
    const float* Wr0  = (const float*)d_in[5];
    const float* Wl1  = (const float*)d_in[6];
    const float* bl1  = (const float*)d_in[7];
    const float* Wr1  = (const float*)d_in[8];
    const float* Wl2  = (const float*)d_in[9];
    const float* bl2  = (const float*)d_in[10];
    const float* Wr2  = (const float*)d_in[11];

    const int N = in_sizes[0] / K_DIM;       // 50000
    const int E = in_sizes[1] / 2;           // 600000
    const int* src = ei;
    const int* dst = ei + E;

    float* out = (float*)d_out;              // h3 [N,40] then g [128,40]
    float* gsum = out + (size_t)N * 40;

    // carve workspace (256B aligned regions)
    char* w = (char*)d_ws;
    auto alloc = [&](size_t bytes) {
        char* p = w;
        w += (bytes + 255) & ~(size_t)255;
        return p;
    };
    float* bufA  = (float*)alloc((size_t)N * K_DIM * 4);  // agg (all layers)
    float* bufB  = (float*)alloc((size_t)N * K_DIM * 4);  // h1
    float* bufC  = (float*)alloc((size_t)N * K_DIM * 4);  // h2
    int*   rowptr= (int*)alloc((size_t)(N + 1) * 4);
    int*   deg   = (int*)alloc((size_t)N * 4);
    int*   fillp = (int*)alloc((size_t)N * 4);
    int*   csr   = (int*)alloc((size_t)E * 4);
    int*   bsum  = (int*)alloc(256 * 4);
    int*   gstart= (int*)alloc((size_t)(N_GRAPHS + 1) * 4);

    hipMemsetAsync(deg, 0, (size_t)N * 4, stream);

    const int NB = (N + 255) / 256;   // 196

    // build CSR by dst
    deg_kernel<<<(E + 255) / 256, 256, 0, stream>>>(dst, deg, E);
    scan_p1<<<NB, 256, 0, stream>>>(deg, bsum, N);
    scan_p2<<<1, 256, 0, stream>>>(bsum, NB);
    scan_p3<<<NB, 256, 0, stream>>>(deg, bsum, rowptr, fillp, N);
    fill_kernel<<<(E + 255) / 256, 256, 0, stream>>>(src, dst, fillp, csr, E);
    bounds_kernel<<<1, 192, 0, stream>>>(batch, gstart, N);

    const int aggGrid  = (N * 64 + 255) / 256;
    const int gemmGrid = (N + 63) / 64;

    // layer 0
    agg_kernel<true><<<aggGrid, 256, 0, stream>>>(x, rowptr, csr, bufA, N);
    sage_gemm<64, 128, 16, 4, 8, 128, true><<<gemmGrid, 256, 0, stream>>>(
        bufA, x, Wl0, Wr0, bl0, bufB, N);
    // layer 1 (h1 already ReLU'd -> no ReLU in agg)
    agg_kernel<false><<<aggGrid, 256, 0, stream>>>(bufB, rowptr, csr, bufA, N);
    sage_gemm<64, 128, 16, 4, 8, 128, true><<<gemmGrid, 256, 0, stream>>>(
        bufA, bufB, Wl1, Wr1, bl1, bufC, N);
    // layer 2 (writes node output directly to d_out)
    agg_kernel<false><<<aggGrid, 256, 0, stream>>>(bufC, rowptr, csr, bufA, N);
    sage_gemm<64, 64, 16, 4, 4, 40, false><<<gemmGrid, 256, 0, stream>>>(
        bufA, bufC, Wl2, Wr2, bl2, out, N);

    // global mean pool (batch sorted -> contiguous segments)
    pool_kernel<<<N_GRAPHS, 320, 0, stream>>>(out, gstart, gsum);
}

// Round 5
// 387.023 us; speedup vs baseline: 2.0938x; 1.1598x over previous
//
#include <hip/hip_runtime.h>
#include <hip/hip_bf16.h>

// ---------------------------------------------------------------------------
// GraphSAGE 3-layer + global mean pool, fp32 in/out.
//   layer: agg = mean_{e:dst=n} relu(h[src_e]);  h' = agg@Wl^T + bl + h@Wr^T
// R1: sorted-batch pool -> segment reduction.                 810->537us
// R2: parallel scan + wave64 agg + relu-elision.              537->449us
// R3/R4: fp32 GEMM (51 TF, 7.6M bank conflicts) -> bf16 MFMA with hi/lo split
//     (3 MFMAs: hi*hi + hi*lo + lo*hi, ~2^-17 rel err == fp32-class).
//     A staged fp32->hi/lo bf16 in LDS (stride 40 shorts = 20 banks,
//     conflict-free b128 frags); W pre-converted once to hi/lo planes.
//     R4 fixes vector-element reference-binding compile error.
// ---------------------------------------------------------------------------

#define NODES 50000
#define K_DIM 128
#define N_GRAPHS 128

typedef __attribute__((ext_vector_type(8))) short short8;
typedef __attribute__((ext_vector_type(4))) short short4v;
typedef __attribute__((ext_vector_type(4))) float f32x4;

__device__ inline short f2bf(float f) {
    unsigned u = __builtin_bit_cast(unsigned, f);
    u += 0x7FFFu + ((u >> 16) & 1u);          // RNE
    return (short)(u >> 16);
}
__device__ inline float bf2f(short h) {
    unsigned u = ((unsigned)(unsigned short)h) << 16;
    return __builtin_bit_cast(float, u);
}
// returns lo in [15:0] is hi-part? pack: bits[15:0]=hi bf16, bits[31:16]=lo bf16
__device__ inline unsigned hilo_pack(float f) {
    short h = f2bf(f);
    short l = f2bf(f - bf2f(h));
    return ((unsigned)(unsigned short)h) | (((unsigned)(unsigned short)l) << 16);
}

// ---------------- CSR build ----------------
__global__ void deg_kernel(const int* __restrict__ dst, int* __restrict__ deg, int E) {
    int e = blockIdx.x * blockDim.x + threadIdx.x;
    if (e < E) atomicAdd(&deg[dst[e]], 1);
}

__global__ void scan_p1(const int* __restrict__ deg, int* __restrict__ bsum, int N) {
    int i = blockIdx.x * 256 + threadIdx.x;
    int v = (i < N) ? deg[i] : 0;
    #pragma unroll
    for (int off = 32; off > 0; off >>= 1) v += __shfl_down(v, off, 64);
    __shared__ int ws[4];
    int lane = threadIdx.x & 63, wv = threadIdx.x >> 6;
    if (lane == 0) ws[wv] = v;
    __syncthreads();
    if (threadIdx.x == 0) bsum[blockIdx.x] = ws[0] + ws[1] + ws[2] + ws[3];
}

__global__ void scan_p2(int* __restrict__ bsum, int NB) {
    int tid = threadIdx.x, lane = tid & 63, wv = tid >> 6;
    int v = (tid < NB) ? bsum[tid] : 0;
    int incl = v;
    #pragma unroll
    for (int off = 1; off < 64; off <<= 1) {
        int t = __shfl_up(incl, off, 64);
        if (lane >= off) incl += t;
    }
    __shared__ int ws[4];
    if (lane == 63) ws[wv] = incl;
    __syncthreads();
    int add = 0;
    for (int i = 0; i < wv; ++i) add += ws[i];
    incl += add;
    if (tid < NB) bsum[tid] = incl - v;
}

__global__ void scan_p3(const int* __restrict__ deg, const int* __restrict__ boff,
                        int* __restrict__ rowptr, int* __restrict__ fillpos, int N) {
    int i = blockIdx.x * 256 + threadIdx.x;
    int tid = threadIdx.x, lane = tid & 63, wv = tid >> 6;
    int v = (i < N) ? deg[i] : 0;
    int incl = v;
    #pragma unroll
    for (int off = 1; off < 64; off <<= 1) {
        int t = __shfl_up(incl, off, 64);
        if (lane >= off) incl += t;
    }
    __shared__ int ws[4];
    if (lane == 63) ws[wv] = incl;
    __syncthreads();
    int add = 0;
    for (int k = 0; k < wv; ++k) add += ws[k];
    int excl = boff[blockIdx.x] + incl + add - v;
    if (i < N) { rowptr[i] = excl; fillpos[i] = excl; }
    if (i == N) rowptr[N] = excl;
}

__global__ void fill_kernel(const int* __restrict__ src, const int* __restrict__ dst,
                            int* __restrict__ fillpos, int* __restrict__ csr_src, int E) {
    int e = blockIdx.x * blockDim.x + threadIdx.x;
    if (e < E) {
        int p = atomicAdd(&fillpos[dst[e]], 1);
        csr_src[p] = src[e];
    }
}

// ---------------- aggregation: one wave64 per node ----------------
template <bool RELU>
__global__ void agg_kernel(const float* __restrict__ h, const int* __restrict__ rowptr,
                           const int* __restrict__ csr_src, float* __restrict__ agg, int N) {
    int w = (blockIdx.x * blockDim.x + threadIdx.x) >> 6;
    if (w >= N) return;
    int lane = threadIdx.x & 63;
    int half = lane >> 5, l32 = lane & 31;
    int s = rowptr[w], e = rowptr[w + 1];
    float4 acc = make_float4(0.f, 0.f, 0.f, 0.f);
    int i = s + half;
    for (; i + 2 < e; i += 4) {
        int s0 = csr_src[i], s1 = csr_src[i + 2];
        float4 v0 = reinterpret_cast<const float4*>(h + (size_t)s0 * K_DIM)[l32];
        float4 v1 = reinterpret_cast<const float4*>(h + (size_t)s1 * K_DIM)[l32];
        if (RELU) {
            acc.x += fmaxf(v0.x, 0.f) + fmaxf(v1.x, 0.f);
            acc.y += fmaxf(v0.y, 0.f) + fmaxf(v1.y, 0.f);
            acc.z += fmaxf(v0.z, 0.f) + fmaxf(v1.z, 0.f);
            acc.w += fmaxf(v0.w, 0.f) + fmaxf(v1.w, 0.f);
        } else {
            acc.x += v0.x + v1.x; acc.y += v0.y + v1.y;
            acc.z += v0.z + v1.z; acc.w += v0.w + v1.w;
        }
    }
    for (; i < e; i += 2) {
        int s0 = csr_src[i];
        float4 v0 = reinterpret_cast<const float4*>(h + (size_t)s0 * K_DIM)[l32];
        if (RELU) {
            acc.x += fmaxf(v0.x, 0.f); acc.y += fmaxf(v0.y, 0.f);
            acc.z += fmaxf(v0.z, 0.f); acc.w += fmaxf(v0.w, 0.f);
        } else {
            acc.x += v0.x; acc.y += v0.y; acc.z += v0.z; acc.w += v0.w;
        }
    }
    acc.x += __shfl_xor(acc.x, 32, 64);
    acc.y += __shfl_xor(acc.y, 32, 64);
    acc.z += __shfl_xor(acc.z, 32, 64);
    acc.w += __shfl_xor(acc.w, 32, 64);
    if (half == 0) {
        float inv = 1.0f / fmaxf((float)(e - s), 1.0f);
        acc.x *= inv; acc.y *= inv; acc.z *= inv; acc.w *= inv;
        reinterpret_cast<float4*>(agg + (size_t)w * K_DIM)[l32] = acc;
    }
}

// ---------------- weight pre-conversion to hi/lo bf16 planes ----------------
// layout (shorts): m 0..3 (Wl0,Wr0,Wl1,Wr1): [128][128] at off m*16384
//                  m 4,5  (Wl2,Wr2): [48][128] zero-padded rows, off 65536/71680
__global__ void wconv_kernel(const float* __restrict__ w0, const float* __restrict__ w1,
                             const float* __restrict__ w2, const float* __restrict__ w3,
                             const float* __restrict__ w4, const float* __restrict__ w5,
                             short* __restrict__ whi, short* __restrict__ wlo) {
    int idx = blockIdx.x * 256 + threadIdx.x;
    const int TOT = 4 * 16384 + 2 * 6144;   // 77824
    if (idx >= TOT) return;
    float v;
    if (idx < 65536) {
        int m = idx >> 14, e = idx & 16383;
        const float* W = (m == 0) ? w0 : (m == 1) ? w1 : (m == 2) ? w2 : w3;
        v = W[e];
    } else {
        int i2 = idx - 65536;
        const float* W = (i2 < 6144) ? w4 : w5;
        int e = i2 % 6144;
        int row = e >> 7;
        v = (row < 40) ? W[e] : 0.f;
    }
    unsigned p = hilo_pack(v);
    whi[idx] = (short)(p & 0xFFFFu);
    wlo[idx] = (short)(p >> 16);
}

// ---------------- MFMA GEMM: out = A@Wl^T + bl + H@Wr^T (opt relu) ----------
// hi/lo split bf16, 16x16x32 MFMA. BM=64 rows/block, 4 waves.
// Wave grid: WAVES_M x WAVES_N; wave owns WM_TILES x WN_TILES 16x16 C tiles.
template <int WAVES_M, int WAVES_N, int WM_TILES, int WN_TILES, int DOUT, bool RELU>
__global__ __launch_bounds__(256) void sage_mfma(
        const float* __restrict__ A, const float* __restrict__ H,
        const short* __restrict__ Bhl, const short* __restrict__ Bll,
        const short* __restrict__ Bhr, const short* __restrict__ Blr,
        const float* __restrict__ bl, float* __restrict__ out, int N) {
    constexpr int BM = WAVES_M * WM_TILES * 16;      // 64
    constexpr int LSTR = 40;                          // shorts per LDS row (20 banks)
    const int tid = threadIdx.x;
    const int lane = tid & 63;
    const int wave = tid >> 6;
    const int wm = wave % WAVES_M;
    const int wn = wave / WAVES_M;
    const int l15 = lane & 15;
    const int quad = lane >> 4;
    const int m0 = blockIdx.x * BM;

    __shared__ __align__(16) short Ahi[BM * LSTR];
    __shared__ __align__(16) short Alo[BM * LSTR];

    f32x4 acc[WM_TILES][WN_TILES];
    #pragma unroll
    for (int i = 0; i < WM_TILES; ++i)
        #pragma unroll
        for (int j = 0; j < WN_TILES; ++j)
            acc[i][j] = (f32x4){0.f, 0.f, 0.f, 0.f};

    #pragma unroll
    for (int ph = 0; ph < 2; ++ph) {
        const float* __restrict__ X = ph ? H : A;
        const short* __restrict__ Bh = ph ? Bhr : Bhl;
        const short* __restrict__ Bv = ph ? Blr : Bll;
        for (int k0 = 0; k0 < K_DIM; k0 += 32) {
            // stage A tile [BM][32] fp32 -> hi/lo bf16 LDS
            __syncthreads();
            #pragma unroll
            for (int r = 0; r < BM * 8 / 256; ++r) {   // 2
                int idx = r * 256 + tid;
                int row = idx >> 3, c4 = idx & 7;
                int m = m0 + row;
                float4 v = make_float4(0.f, 0.f, 0.f, 0.f);
                if (m < N) v = *reinterpret_cast<const float4*>(X + (size_t)m * K_DIM + k0 + c4 * 4);
                unsigned px = hilo_pack(v.x);
                unsigned py = hilo_pack(v.y);
                unsigned pz = hilo_pack(v.z);
                unsigned pw = hilo_pack(v.w);
                short4v h4, l4;
                h4[0] = (short)(px & 0xFFFFu); l4[0] = (short)(px >> 16);
                h4[1] = (short)(py & 0xFFFFu); l4[1] = (short)(py >> 16);
                h4[2] = (short)(pz & 0xFFFFu); l4[2] = (short)(pz >> 16);
                h4[3] = (short)(pw & 0xFFFFu); l4[3] = (short)(pw >> 16);
                *reinterpret_cast<short4v*>(&Ahi[row * LSTR + c4 * 4]) = h4;
                *reinterpret_cast<short4v*>(&Alo[row * LSTR + c4 * 4]) = l4;
            }
            // B fragments straight from pre-converted global planes (L2-hot)
            short8 bh[WN_TILES], bo[WN_TILES];
            #pragma unroll
            for (int nt = 0; nt < WN_TILES; ++nt) {
                int n = wn * WN_TILES * 16 + nt * 16 + l15;
                const short* p = Bh + (size_t)n * K_DIM + k0 + quad * 8;
                const short* q = Bv + (size_t)n * K_DIM + k0 + quad * 8;
                bh[nt] = *reinterpret_cast<const short8*>(p);
                bo[nt] = *reinterpret_cast<const short8*>(q);
            }
            __syncthreads();
            // A fragments + 3-term MFMA
            #pragma unroll
            for (int mt = 0; mt < WM_TILES; ++mt) {
                int row = wm * WM_TILES * 16 + mt * 16 + l15;
                short8 ah = *reinterpret_cast<const short8*>(&Ahi[row * LSTR + quad * 8]);
                short8 ao = *reinterpret_cast<const short8*>(&Alo[row * LSTR + quad * 8]);
                #pragma unroll
                for (int nt = 0; nt < WN_TILES; ++nt) {
                    acc[mt][nt] = __builtin_amdgcn_mfma_f32_16x16x32_bf16(ah, bh[nt], acc[mt][nt], 0, 0, 0);
                    acc[mt][nt] = __builtin_amdgcn_mfma_f32_16x16x32_bf16(ah, bo[nt], acc[mt][nt], 0, 0, 0);
                    acc[mt][nt] = __builtin_amdgcn_mfma_f32_16x16x32_bf16(ao, bh[nt], acc[mt][nt], 0, 0, 0);
                }
            }
        }
    }

    // epilogue: bias + relu + store (C/D: col=lane&15, row=quad*4+reg)
    float bias[WN_TILES];
    #pragma unroll
    for (int nt = 0; nt < WN_TILES; ++nt) {
        int col = wn * WN_TILES * 16 + nt * 16 + l15;
        bias[nt] = (col < DOUT) ? bl[col] : 0.f;
    }
    #pragma unroll
    for (int mt = 0; mt < WM_TILES; ++mt) {
        #pragma unroll
        for (int nt = 0; nt < WN_TILES; ++nt) {
            int col = wn * WN_TILES * 16 + nt * 16 + l15;
            #pragma unroll
            for (int reg = 0; reg < 4; ++reg) {
                int row = m0 + wm * WM_TILES * 16 + mt * 16 + quad * 4 + reg;
                if (row < N && col < DOUT) {
                    float v = acc[mt][nt][reg] + bias[nt];
                    if (RELU) v = fmaxf(v, 0.f);
                    out[(size_t)row * DOUT + col] = v;
                }
            }
        }
    }
}

// ---------------- pool ----------------
__global__ void bounds_kernel(const int* __restrict__ batch, int* __restrict__ gstart, int N) {
    int g = blockIdx.x * blockDim.x + threadIdx.x;
    if (g > N_GRAPHS) return;
    int lo = 0, hi = N;
    while (lo < hi) {
        int mid = (lo + hi) >> 1;
        if (batch[mid] < g) lo = mid + 1; else hi = mid;
    }
    gstart[g] = lo;
}

__global__ __launch_bounds__(320) void pool_kernel(const float* __restrict__ h,
                                                   const int* __restrict__ gstart,
                                                   float* __restrict__ g_out) {
    int g = blockIdx.x;
    int tid = threadIdx.x;
    int c = tid % 40, r = tid / 40;
    int s = gstart[g], e = gstart[g + 1];
    float acc = 0.f;
    for (int n = s + r; n < e; n += 8)
        acc += h[(size_t)n * 40 + c];
    __shared__ float sh[8][40];
    sh[r][c] = acc;
    __syncthreads();
    if (r == 0) {
        float sum = 0.f;
        #pragma unroll
        for (int i = 0; i < 8; ++i) sum += sh[i][c];
        g_out[g * 40 + c] = sum / fmaxf((float)(e - s), 1.0f);
    }
}

extern "C" void kernel_launch(void* const* d_in, const int* in_sizes, int n_in,
                              void* d_out, int out_size, void* d_ws, size_t ws_size,
                              hipStream_t stream) {
    const float* x    = (const float*)d_in[0];
    const int*   ei   = (const int*)d_in[1];
    const int*   batch= (const int*)d_in[2];
    const float* Wl0  = (const float*)d_in[3];
    const float* bl0  = (const float*)d_in[4];
    const float* Wr0  = (const float*)d_in[5];
    const float* Wl1  = (const float*)d_in[6];
    const float* bl1  = (const float*)d_in[7];
    const float* Wr1  = (const float*)d_in[8];
    const float* Wl2  = (const float*)d_in[9];
    const float* bl2  = (const float*)d_in[10];
    const float* Wr2  = (const float*)d_in[11];

    const int N = in_sizes[0] / K_DIM;       // 50000
    const int E = in_sizes[1] / 2;           // 600000
    const int* src = ei;
    const int* dst = ei + E;

    float* out = (float*)d_out;              // h3 [N,40] then g [128,40]
    float* gsum = out + (size_t)N * 40;

    char* w = (char*)d_ws;
    auto alloc = [&](size_t bytes) {
        char* p = w;
        w += (bytes + 255) & ~(size_t)255;
        return p;
    };
    float* bufA  = (float*)alloc((size_t)N * K_DIM * 4);  // agg (all layers)
    float* bufB  = (float*)alloc((size_t)N * K_DIM * 4);  // h1
    float* bufC  = (float*)alloc((size_t)N * K_DIM * 4);  // h2
    int*   rowptr= (int*)alloc((size_t)(N + 1) * 4);
    int*   deg   = (int*)alloc((size_t)N * 4);
    int*   fillp = (int*)alloc((size_t)N * 4);
    int*   csr   = (int*)alloc((size_t)E * 4);
    int*   bsum  = (int*)alloc(256 * 4);
    int*   gstart= (int*)alloc((size_t)(N_GRAPHS + 1) * 4);
    short* whi   = (short*)alloc(77824 * 2);
    short* wlo   = (short*)alloc(77824 * 2);

    (void)hipMemsetAsync(deg, 0, (size_t)N * 4, stream);

    const int NB = (N + 255) / 256;   // 196

    // CSR build + weight conversion + pool bounds
    deg_kernel<<<(E + 255) / 256, 256, 0, stream>>>(dst, deg, E);
    scan_p1<<<NB, 256, 0, stream>>>(deg, bsum, N);
    scan_p2<<<1, 256, 0, stream>>>(bsum, NB);
    scan_p3<<<NB, 256, 0, stream>>>(deg, bsum, rowptr, fillp, N);
    fill_kernel<<<(E + 255) / 256, 256, 0, stream>>>(src, dst, fillp, csr, E);
    wconv_kernel<<<(77824 + 255) / 256, 256, 0, stream>>>(Wl0, Wr0, Wl1, Wr1, Wl2, Wr2, whi, wlo);
    bounds_kernel<<<1, 192, 0, stream>>>(batch, gstart, N);

    // weight plane offsets (shorts): Wl0:0 Wr0:16384 Wl1:32768 Wr1:49152 Wl2:65536 Wr2:71680
    short* hWl0 = whi;          short* lWl0 = wlo;
    short* hWr0 = whi + 16384;  short* lWr0 = wlo + 16384;
    short* hWl1 = whi + 32768;  short* lWl1 = wlo + 32768;
    short* hWr1 = whi + 49152;  short* lWr1 = wlo + 49152;
    short* hWl2 = whi + 65536;  short* lWl2 = wlo + 65536;
    short* hWr2 = whi + 71680;  short* lWr2 = wlo + 71680;

    const int aggGrid  = (N * 64 + 255) / 256;
    const int gemmGrid = (N + 63) / 64;       // 782

    // layer 0
    agg_kernel<true><<<aggGrid, 256, 0, stream>>>(x, rowptr, csr, bufA, N);
    sage_mfma<1, 4, 4, 2, 128, true><<<gemmGrid, 256, 0, stream>>>(
        bufA, x, hWl0, lWl0, hWr0, lWr0, bl0, bufB, N);
    // layer 1
    agg_kernel<false><<<aggGrid, 256, 0, stream>>>(bufB, rowptr, csr, bufA, N);
    sage_mfma<1, 4, 4, 2, 128, true><<<gemmGrid, 256, 0, stream>>>(
        bufA, bufB, hWl1, lWl1, hWr1, lWr1, bl1, bufC, N);
    // layer 2 -> d_out node features
    agg_kernel<false><<<aggGrid, 256, 0, stream>>>(bufC, rowptr, csr, bufA, N);
    sage_mfma<4, 1, 1, 3, 40, false><<<gemmGrid, 256, 0, stream>>>(
        bufA, bufC, hWl2, lWl2, hWr2, lWr2, bl2, out, N);

    // global mean pool
    pool_kernel<<<N_GRAPHS, 320, 0, stream>>>(out, gstart, gsum);
}

// Round 6
// 378.310 us; speedup vs baseline: 2.1420x; 1.0230x over previous
//
#include <hip/hip_runtime.h>
#include <hip/hip_bf16.h>

// ---------------------------------------------------------------------------
// GraphSAGE 3-layer + global mean pool, fp32 in/out.
//   layer: agg = mean_{e:dst=n} relu(h[src_e]);  h' = agg@Wl^T + bl + h@Wr^T
// R1: sorted-batch pool -> segment reduction.                 810->537us
// R2: parallel scan + wave64 agg + relu-elision.              537->449us
// R3-R5: bf16 MFMA hi/lo split GEMM (3 MFMAs, fp32-class).    449->387us
// R6: (a) layer-2 linearity swap: h2>=0 so agg(h2)@Wl^T == agg(h2@Wl^T);
//     gather 40-dim rows (160B) instead of 128-dim (512B), 3.2x fewer bytes,
//     8MB table L2-friendly. (b) L0/L1 gather unroll x4 (4 loads in flight;
//     was latency-bound at 3.6 TB/s, VALUBusy 27%).
// ---------------------------------------------------------------------------

#define NODES 50000
#define K_DIM 128
#define N_GRAPHS 128

typedef __attribute__((ext_vector_type(8))) short short8;
typedef __attribute__((ext_vector_type(4))) short short4v;
typedef __attribute__((ext_vector_type(4))) float f32x4;

__device__ inline short f2bf(float f) {
    unsigned u = __builtin_bit_cast(unsigned, f);
    u += 0x7FFFu + ((u >> 16) & 1u);          // RNE
    return (short)(u >> 16);
}
__device__ inline float bf2f(short h) {
    unsigned u = ((unsigned)(unsigned short)h) << 16;
    return __builtin_bit_cast(float, u);
}
// pack: bits[15:0]=hi bf16, bits[31:16]=lo bf16
__device__ inline unsigned hilo_pack(float f) {
    short h = f2bf(f);
    short l = f2bf(f - bf2f(h));
    return ((unsigned)(unsigned short)h) | (((unsigned)(unsigned short)l) << 16);
}

// ---------------- CSR build ----------------
__global__ void deg_kernel(const int* __restrict__ dst, int* __restrict__ deg, int E) {
    int e = blockIdx.x * blockDim.x + threadIdx.x;
    if (e < E) atomicAdd(&deg[dst[e]], 1);
}

__global__ void scan_p1(const int* __restrict__ deg, int* __restrict__ bsum, int N) {
    int i = blockIdx.x * 256 + threadIdx.x;
    int v = (i < N) ? deg[i] : 0;
    #pragma unroll
    for (int off = 32; off > 0; off >>= 1) v += __shfl_down(v, off, 64);
    __shared__ int ws[4];
    int lane = threadIdx.x & 63, wv = threadIdx.x >> 6;
    if (lane == 0) ws[wv] = v;
    __syncthreads();
    if (threadIdx.x == 0) bsum[blockIdx.x] = ws[0] + ws[1] + ws[2] + ws[3];
}

__global__ void scan_p2(int* __restrict__ bsum, int NB) {
    int tid = threadIdx.x, lane = tid & 63, wv = tid >> 6;
    int v = (tid < NB) ? bsum[tid] : 0;
    int incl = v;
    #pragma unroll
    for (int off = 1; off < 64; off <<= 1) {
        int t = __shfl_up(incl, off, 64);
        if (lane >= off) incl += t;
    }
    __shared__ int ws[4];
    if (lane == 63) ws[wv] = incl;
    __syncthreads();
    int add = 0;
    for (int i = 0; i < wv; ++i) add += ws[i];
    incl += add;
    if (tid < NB) bsum[tid] = incl - v;
}

__global__ void scan_p3(const int* __restrict__ deg, const int* __restrict__ boff,
                        int* __restrict__ rowptr, int* __restrict__ fillpos, int N) {
    int i = blockIdx.x * 256 + threadIdx.x;
    int tid = threadIdx.x, lane = tid & 63, wv = tid >> 6;
    int v = (i < N) ? deg[i] : 0;
    int incl = v;
    #pragma unroll
    for (int off = 1; off < 64; off <<= 1) {
        int t = __shfl_up(incl, off, 64);
        if (lane >= off) incl += t;
    }
    __shared__ int ws[4];
    if (lane == 63) ws[wv] = incl;
    __syncthreads();
    int add = 0;
    for (int k = 0; k < wv; ++k) add += ws[k];
    int excl = boff[blockIdx.x] + incl + add - v;
    if (i < N) { rowptr[i] = excl; fillpos[i] = excl; }
    if (i == N) rowptr[N] = excl;
}

__global__ void fill_kernel(const int* __restrict__ src, const int* __restrict__ dst,
                            int* __restrict__ fillpos, int* __restrict__ csr_src, int E) {
    int e = blockIdx.x * blockDim.x + threadIdx.x;
    if (e < E) {
        int p = atomicAdd(&fillpos[dst[e]], 1);
        csr_src[p] = src[e];
    }
}

// ---------------- aggregation (128-dim): one wave64 per node, 4-deep ILP ----
template <bool RELU>
__global__ void agg_kernel(const float* __restrict__ h, const int* __restrict__ rowptr,
                           const int* __restrict__ csr_src, float* __restrict__ agg, int N) {
    int w = (blockIdx.x * blockDim.x + threadIdx.x) >> 6;
    if (w >= N) return;
    int lane = threadIdx.x & 63;
    int half = lane >> 5, l32 = lane & 31;
    int s = rowptr[w], e = rowptr[w + 1];
    float4 acc = make_float4(0.f, 0.f, 0.f, 0.f);
    int i = s + half;
    // 4 independent row loads in flight per half-wave
    for (; i + 6 < e; i += 8) {
        int s0 = csr_src[i], s1 = csr_src[i + 2], s2 = csr_src[i + 4], s3 = csr_src[i + 6];
        float4 v0 = reinterpret_cast<const float4*>(h + (size_t)s0 * K_DIM)[l32];
        float4 v1 = reinterpret_cast<const float4*>(h + (size_t)s1 * K_DIM)[l32];
        float4 v2 = reinterpret_cast<const float4*>(h + (size_t)s2 * K_DIM)[l32];
        float4 v3 = reinterpret_cast<const float4*>(h + (size_t)s3 * K_DIM)[l32];
        if (RELU) {
            acc.x += fmaxf(v0.x, 0.f) + fmaxf(v1.x, 0.f) + fmaxf(v2.x, 0.f) + fmaxf(v3.x, 0.f);
            acc.y += fmaxf(v0.y, 0.f) + fmaxf(v1.y, 0.f) + fmaxf(v2.y, 0.f) + fmaxf(v3.y, 0.f);
            acc.z += fmaxf(v0.z, 0.f) + fmaxf(v1.z, 0.f) + fmaxf(v2.z, 0.f) + fmaxf(v3.z, 0.f);
            acc.w += fmaxf(v0.w, 0.f) + fmaxf(v1.w, 0.f) + fmaxf(v2.w, 0.f) + fmaxf(v3.w, 0.f);
        } else {
            acc.x += v0.x + v1.x + v2.x + v3.x;
            acc.y += v0.y + v1.y + v2.y + v3.y;
            acc.z += v0.z + v1.z + v2.z + v3.z;
            acc.w += v0.w + v1.w + v2.w + v3.w;
        }
    }
    for (; i < e; i += 2) {
        int s0 = csr_src[i];
        float4 v0 = reinterpret_cast<const float4*>(h + (size_t)s0 * K_DIM)[l32];
        if (RELU) {
            acc.x += fmaxf(v0.x, 0.f); acc.y += fmaxf(v0.y, 0.f);
            acc.z += fmaxf(v0.z, 0.f); acc.w += fmaxf(v0.w, 0.f);
        } else {
            acc.x += v0.x; acc.y += v0.y; acc.z += v0.z; acc.w += v0.w;
        }
    }
    acc.x += __shfl_xor(acc.x, 32, 64);
    acc.y += __shfl_xor(acc.y, 32, 64);
    acc.z += __shfl_xor(acc.z, 32, 64);
    acc.w += __shfl_xor(acc.w, 32, 64);
    if (half == 0) {
        float inv = 1.0f / fmaxf((float)(e - s), 1.0f);
        acc.x *= inv; acc.y *= inv; acc.z *= inv; acc.w *= inv;
        reinterpret_cast<float4*>(agg + (size_t)w * K_DIM)[l32] = acc;
    }
}

// ---------------- agg40: out[n] = mean_e yl[src_e] + yr[n] (layer 2) -------
__global__ void agg40_kernel(const float* __restrict__ yl, const float* __restrict__ yr,
                             const int* __restrict__ rowptr, const int* __restrict__ csr_src,
                             float* __restrict__ out, int N) {
    int w = (blockIdx.x * blockDim.x + threadIdx.x) >> 6;
    if (w >= N) return;
    int lane = threadIdx.x & 63;
    int s = rowptr[w], e = rowptr[w + 1];
    if (lane >= 40) return;
    float acc = 0.f;
    int i = s;
    for (; i + 3 < e; i += 4) {
        int s0 = csr_src[i], s1 = csr_src[i + 1], s2 = csr_src[i + 2], s3 = csr_src[i + 3];
        float v0 = yl[(size_t)s0 * 40 + lane];
        float v1 = yl[(size_t)s1 * 40 + lane];
        float v2 = yl[(size_t)s2 * 40 + lane];
        float v3 = yl[(size_t)s3 * 40 + lane];
        acc += (v0 + v1) + (v2 + v3);
    }
    for (; i < e; ++i) acc += yl[(size_t)csr_src[i] * 40 + lane];
    float inv = 1.0f / fmaxf((float)(e - s), 1.0f);
    out[(size_t)w * 40 + lane] = acc * inv + yr[(size_t)w * 40 + lane];
}

// ---------------- weight pre-conversion to hi/lo bf16 planes ----------------
__global__ void wconv_kernel(const float* __restrict__ w0, const float* __restrict__ w1,
                             const float* __restrict__ w2, const float* __restrict__ w3,
                             const float* __restrict__ w4, const float* __restrict__ w5,
                             short* __restrict__ whi, short* __restrict__ wlo) {
    int idx = blockIdx.x * 256 + threadIdx.x;
    const int TOT = 4 * 16384 + 2 * 6144;   // 77824
    if (idx >= TOT) return;
    float v;
    if (idx < 65536) {
        int m = idx >> 14, e = idx & 16383;
        const float* W = (m == 0) ? w0 : (m == 1) ? w1 : (m == 2) ? w2 : w3;
        v = W[e];
    } else {
        int i2 = idx - 65536;
        const float* W = (i2 < 6144) ? w4 : w5;
        int e = i2 % 6144;
        int row = e >> 7;
        v = (row < 40) ? W[e] : 0.f;
    }
    unsigned p = hilo_pack(v);
    whi[idx] = (short)(p & 0xFFFFu);
    wlo[idx] = (short)(p >> 16);
}

// ---------------- MFMA GEMM ----------------
// PHASES=2: out = A@Wl^T (+bias) + H@Wr^T;  PHASES=1: out = A@Wl^T (+bias)
// hi/lo split bf16, 16x16x32 MFMA. BM rows/block, 4 waves.
template <int WAVES_M, int WAVES_N, int WM_TILES, int WN_TILES, int DOUT, bool RELU,
          int PHASES, bool BIAS>
__global__ __launch_bounds__(256) void sage_mfma(
        const float* __restrict__ A, const float* __restrict__ H,
        const short* __restrict__ Bhl, const short* __restrict__ Bll,
        const short* __restrict__ Bhr, const short* __restrict__ Blr,
        const float* __restrict__ bl, float* __restrict__ out, int N) {
    constexpr int BM = WAVES_M * WM_TILES * 16;      // 64
    constexpr int LSTR = 40;                          // shorts per LDS row (20 banks)
    const int tid = threadIdx.x;
    const int lane = tid & 63;
    const int wave = tid >> 6;
    const int wm = wave % WAVES_M;
    const int wn = wave / WAVES_M;
    const int l15 = lane & 15;
    const int quad = lane >> 4;
    const int m0 = blockIdx.x * BM;

    __shared__ __align__(16) short Ahi[BM * LSTR];
    __shared__ __align__(16) short Alo[BM * LSTR];

    f32x4 acc[WM_TILES][WN_TILES];
    #pragma unroll
    for (int i = 0; i < WM_TILES; ++i)
        #pragma unroll
        for (int j = 0; j < WN_TILES; ++j)
            acc[i][j] = (f32x4){0.f, 0.f, 0.f, 0.f};

    #pragma unroll
    for (int ph = 0; ph < PHASES; ++ph) {
        const float* __restrict__ X = ph ? H : A;
        const short* __restrict__ Bh = ph ? Bhr : Bhl;
        const short* __restrict__ Bv = ph ? Blr : Bll;
        for (int k0 = 0; k0 < K_DIM; k0 += 32) {
            __syncthreads();
            #pragma unroll
            for (int r = 0; r < BM * 8 / 256; ++r) {   // 2
                int idx = r * 256 + tid;
                int row = idx >> 3, c4 = idx & 7;
                int m = m0 + row;
                float4 v = make_float4(0.f, 0.f, 0.f, 0.f);
                if (m < N) v = *reinterpret_cast<const float4*>(X + (size_t)m * K_DIM + k0 + c4 * 4);
                unsigned px = hilo_pack(v.x);
                unsigned py = hilo_pack(v.y);
                unsigned pz = hilo_pack(v.z);
                unsigned pw = hilo_pack(v.w);
                short4v h4, l4;
                h4[0] = (short)(px & 0xFFFFu); l4[0] = (short)(px >> 16);
                h4[1] = (short)(py & 0xFFFFu); l4[1] = (short)(py >> 16);
                h4[2] = (short)(pz & 0xFFFFu); l4[2] = (short)(pz >> 16);
                h4[3] = (short)(pw & 0xFFFFu); l4[3] = (short)(pw >> 16);
                *reinterpret_cast<short4v*>(&Ahi[row * LSTR + c4 * 4]) = h4;
                *reinterpret_cast<short4v*>(&Alo[row * LSTR + c4 * 4]) = l4;
            }
            short8 bh[WN_TILES], bo[WN_TILES];
            #pragma unroll
            for (int nt = 0; nt < WN_TILES; ++nt) {
                int n = wn * WN_TILES * 16 + nt * 16 + l15;
                const short* p = Bh + (size_t)n * K_DIM + k0 + quad * 8;
                const short* q = Bv + (size_t)n * K_DIM + k0 + quad * 8;
                bh[nt] = *reinterpret_cast<const short8*>(p);
                bo[nt] = *reinterpret_cast<const short8*>(q);
            }
            __syncthreads();
            #pragma unroll
            for (int mt = 0; mt < WM_TILES; ++mt) {
                int row = wm * WM_TILES * 16 + mt * 16 + l15;
                short8 ah = *reinterpret_cast<const short8*>(&Ahi[row * LSTR + quad * 8]);
                short8 ao = *reinterpret_cast<const short8*>(&Alo[row * LSTR + quad * 8]);
                #pragma unroll
                for (int nt = 0; nt < WN_TILES; ++nt) {
                    acc[mt][nt] = __builtin_amdgcn_mfma_f32_16x16x32_bf16(ah, bh[nt], acc[mt][nt], 0, 0, 0);
                    acc[mt][nt] = __builtin_amdgcn_mfma_f32_16x16x32_bf16(ah, bo[nt], acc[mt][nt], 0, 0, 0);
                    acc[mt][nt] = __builtin_amdgcn_mfma_f32_16x16x32_bf16(ao, bh[nt], acc[mt][nt], 0, 0, 0);
                }
            }
        }
    }

    // epilogue: bias + relu + store (C/D: col=lane&15, row=quad*4+reg)
    float bias[WN_TILES];
    #pragma unroll
    for (int nt = 0; nt < WN_TILES; ++nt) {
        int col = wn * WN_TILES * 16 + nt * 16 + l15;
        bias[nt] = (BIAS && col < DOUT) ? bl[col] : 0.f;
    }
    #pragma unroll
    for (int mt = 0; mt < WM_TILES; ++mt) {
        #pragma unroll
        for (int nt = 0; nt < WN_TILES; ++nt) {
            int col = wn * WN_TILES * 16 + nt * 16 + l15;
            #pragma unroll
            for (int reg = 0; reg < 4; ++reg) {
                int row = m0 + wm * WM_TILES * 16 + mt * 16 + quad * 4 + reg;
                if (row < N && col < DOUT) {
                    float v = acc[mt][nt][reg] + bias[nt];
                    if (RELU) v = fmaxf(v, 0.f);
                    out[(size_t)row * DOUT + col] = v;
                }
            }
        }
    }
}

// ---------------- pool ----------------
__global__ void bounds_kernel(const int* __restrict__ batch, int* __restrict__ gstart, int N) {
    int g = blockIdx.x * blockDim.x + threadIdx.x;
    if (g > N_GRAPHS) return;
    int lo = 0, hi = N;
    while (lo < hi) {
        int mid = (lo + hi) >> 1;
        if (batch[mid] < g) lo = mid + 1; else hi = mid;
    }
    gstart[g] = lo;
}

__global__ __launch_bounds__(320) void pool_kernel(const float* __restrict__ h,
                                                   const int* __restrict__ gstart,
                                                   float* __restrict__ g_out) {
    int g = blockIdx.x;
    int tid = threadIdx.x;
    int c = tid % 40, r = tid / 40;
    int s = gstart[g], e = gstart[g + 1];
    float acc = 0.f;
    for (int n = s + r; n < e; n += 8)
        acc += h[(size_t)n * 40 + c];
    __shared__ float sh[8][40];
    sh[r][c] = acc;
    __syncthreads();
    if (r == 0) {
        float sum = 0.f;
        #pragma unroll
        for (int i = 0; i < 8; ++i) sum += sh[i][c];
        g_out[g * 40 + c] = sum / fmaxf((float)(e - s), 1.0f);
    }
}

extern "C" void kernel_launch(void* const* d_in, const int* in_sizes, int n_in,
                              void* d_out, int out_size, void* d_ws, size_t ws_size,
                              hipStream_t stream) {
    const float* x    = (const float*)d_in[0];
    const int*   ei   = (const int*)d_in[1];
    const int*   batch= (const int*)d_in[2];
    const float* Wl0  = (const float*)d_in[3];
    const float* bl0  = (const float*)d_in[4];
    const float* Wr0  = (const float*)d_in[5];
    const float* Wl1  = (const float*)d_in[6];
    const float* bl1  = (const float*)d_in[7];
    const float* Wr1  = (const float*)d_in[8];
    const float* Wl2  = (const float*)d_in[9];
    const float* bl2  = (const float*)d_in[10];
    const float* Wr2  = (const float*)d_in[11];

    const int N = in_sizes[0] / K_DIM;       // 50000
    const int E = in_sizes[1] / 2;           // 600000
    const int* src = ei;
    const int* dst = ei + E;

    float* out = (float*)d_out;              // h3 [N,40] then g [128,40]
    float* gsum = out + (size_t)N * 40;

    char* w = (char*)d_ws;
    auto alloc = [&](size_t bytes) {
        char* p = w;
        w += (bytes + 255) & ~(size_t)255;
        return p;
    };
    float* bufA  = (float*)alloc((size_t)N * K_DIM * 4);  // agg L0/L1; yl2/yr2 in L2
    float* bufB  = (float*)alloc((size_t)N * K_DIM * 4);  // h1
    float* bufC  = (float*)alloc((size_t)N * K_DIM * 4);  // h2
    int*   rowptr= (int*)alloc((size_t)(N + 1) * 4);
    int*   deg   = (int*)alloc((size_t)N * 4);
    int*   fillp = (int*)alloc((size_t)N * 4);
    int*   csr   = (int*)alloc((size_t)E * 4);
    int*   bsum  = (int*)alloc(256 * 4);
    int*   gstart= (int*)alloc((size_t)(N_GRAPHS + 1) * 4);
    short* whi   = (short*)alloc(77824 * 2);
    short* wlo   = (short*)alloc(77824 * 2);

    (void)hipMemsetAsync(deg, 0, (size_t)N * 4, stream);

    const int NB = (N + 255) / 256;   // 196

    // CSR build + weight conversion + pool bounds
    deg_kernel<<<(E + 255) / 256, 256, 0, stream>>>(dst, deg, E);
    scan_p1<<<NB, 256, 0, stream>>>(deg, bsum, N);
    scan_p2<<<1, 256, 0, stream>>>(bsum, NB);
    scan_p3<<<NB, 256, 0, stream>>>(deg, bsum, rowptr, fillp, N);
    fill_kernel<<<(E + 255) / 256, 256, 0, stream>>>(src, dst, fillp, csr, E);
    wconv_kernel<<<(77824 + 255) / 256, 256, 0, stream>>>(Wl0, Wr0, Wl1, Wr1, Wl2, Wr2, whi, wlo);
    bounds_kernel<<<1, 192, 0, stream>>>(batch, gstart, N);

    // weight plane offsets (shorts)
    short* hWl0 = whi;          short* lWl0 = wlo;
    short* hWr0 = whi + 16384;  short* lWr0 = wlo + 16384;
    short* hWl1 = whi + 32768;  short* lWl1 = wlo + 32768;
    short* hWr1 = whi + 49152;  short* lWr1 = wlo + 49152;
    short* hWl2 = whi + 65536;  short* lWl2 = wlo + 65536;
    short* hWr2 = whi + 71680;  short* lWr2 = wlo + 71680;

    const int aggGrid  = (N * 64 + 255) / 256;
    const int gemmGrid = (N + 63) / 64;       // 782

    // layer 0
    agg_kernel<true><<<aggGrid, 256, 0, stream>>>(x, rowptr, csr, bufA, N);
    sage_mfma<1, 4, 4, 2, 128, true, 2, true><<<gemmGrid, 256, 0, stream>>>(
        bufA, x, hWl0, lWl0, hWr0, lWr0, bl0, bufB, N);
    // layer 1
    agg_kernel<false><<<aggGrid, 256, 0, stream>>>(bufB, rowptr, csr, bufA, N);
    sage_mfma<1, 4, 4, 2, 128, true, 2, true><<<gemmGrid, 256, 0, stream>>>(
        bufA, bufB, hWl1, lWl1, hWr1, lWr1, bl1, bufC, N);
    // layer 2 (linearity swap): yl2 = h2@Wl2^T; yr2 = h2@Wr2^T + bl2;
    //                           h3[n] = mean_e yl2[src_e] + yr2[n]
    float* yl2 = bufA;                 // N x 40
    float* yr2 = bufA + (size_t)N * 40;
    sage_mfma<4, 1, 1, 3, 40, false, 1, false><<<gemmGrid, 256, 0, stream>>>(
        bufC, bufC, hWl2, lWl2, hWl2, lWl2, bl2, yl2, N);
    sage_mfma<4, 1, 1, 3, 40, false, 1, true><<<gemmGrid, 256, 0, stream>>>(
        bufC, bufC, hWr2, lWr2, hWr2, lWr2, bl2, yr2, N);
    agg40_kernel<<<aggGrid, 256, 0, stream>>>(yl2, yr2, rowptr, csr, out, N);

    // global mean pool
    pool_kernel<<<N_GRAPHS, 320, 0, stream>>>(out, gstart, gsum);
}